// Round 2
// baseline (1036.978 us; speedup 1.0000x reference)
//
#include <hip/hip_runtime.h>
#include <math.h>

#define N_NODES 100000
#define N_EDGES 1200000
#define HIDDEN  64
#define NODE_BLOCKS (N_NODES / 4)   // 25000, exact: 4 nodes (waves) per 256-thread block

// ---------------------------------------------------------------- utilities

__global__ __launch_bounds__(256) void zero_u32(unsigned* __restrict__ p, int n) {
    int i = blockIdx.x * 256 + threadIdx.x;
    if (i < n) p[i] = 0u;
}

// ---------------------------------------------------------------- CSR build

__global__ __launch_bounds__(256) void hist_kernel(const int* __restrict__ dst,
                                                   unsigned* __restrict__ cnt) {
    int e = blockIdx.x * 256 + threadIdx.x;
    if (e < N_EDGES) atomicAdd(&cnt[dst[e]], 1u);
}

// single-block scan over N_NODES counts -> rowptr (exclusive), plus invcnt = 1/(cnt+1)
__global__ __launch_bounds__(1024) void scan_kernel(const unsigned* __restrict__ cnt,
                                                    unsigned* __restrict__ rowptr,
                                                    float* __restrict__ invcnt) {
    __shared__ unsigned lds[1024];
    const int t = threadIdx.x;
    const int CHUNK = (N_NODES + 1023) / 1024;   // 98
    int lo = t * CHUNK;
    int hi = lo + CHUNK; if (hi > N_NODES) hi = N_NODES;
    if (lo > N_NODES) lo = N_NODES;

    unsigned s = 0;
    for (int i = lo; i < hi; ++i) s += cnt[i];
    lds[t] = s;
    __syncthreads();
    // Hillis-Steele inclusive scan over 1024 partials
    for (int off = 1; off < 1024; off <<= 1) {
        unsigned v = (t >= off) ? lds[t - off] : 0u;
        __syncthreads();
        lds[t] += v;
        __syncthreads();
    }
    unsigned run = lds[t] - s;   // exclusive prefix
    for (int i = lo; i < hi; ++i) {
        unsigned cv = cnt[i];
        rowptr[i] = run;
        run += cv;
        invcnt[i] = 1.0f / (float)(cv + 1u);   // +1 for the self loop
    }
    if (t == 1023) rowptr[N_NODES] = N_EDGES;
}

__global__ __launch_bounds__(256) void fill_csr(const int* __restrict__ src,
                                                const int* __restrict__ dst,
                                                const unsigned* __restrict__ rowptr,
                                                unsigned* __restrict__ fillc,
                                                unsigned* __restrict__ csr) {
    int e = blockIdx.x * 256 + threadIdx.x;
    if (e < N_EDGES) {
        int d = dst[e];
        unsigned pos = rowptr[d] + atomicAdd(&fillc[d], 1u);
        csr[pos] = (unsigned)src[e];
    }
}

// ---------------------------------------------------------------- per-layer

// y[n,:] = hprev[n,:] @ W   (W: [IN1, 64] row-major, no bias — bias folded post-mean)
template <int IN1>
__global__ __launch_bounds__(256) void linear_y(const float* __restrict__ hprev,
                                                const float* __restrict__ W,
                                                float* __restrict__ y) {
    __shared__ float Wl[IN1 * 64];
    __shared__ float hpL[4][IN1];
    const int tid = threadIdx.x;
    for (int i = tid; i < IN1 * 64; i += 256) Wl[i] = W[i];
    const int w = tid >> 6, lane = tid & 63;
    const int n = blockIdx.x * 4 + w;          // N divisible by 4; grid exact
    if (lane < IN1) hpL[w][lane] = hprev[n * IN1 + lane];
    __syncthreads();
    float acc = 0.f;
#pragma unroll
    for (int i = 0; i < IN1; ++i) acc += hpL[w][i] * Wl[i * 64 + lane];
    y[n * 64 + lane] = acc;
}

// agg[n,:] = (y[n,:] + sum_{e in-edges} y[src_e,:]) * invcnt[n] + b
// hnext[n,:] = relu( [hprev[n,:], agg[n,:]] @ U + c )     (U: [IN1+64, 64] row-major)
template <int IN1>
__global__ __launch_bounds__(256) void fused_agg_update(const float* __restrict__ hprev,
                                                        const float* __restrict__ y,
                                                        const unsigned* __restrict__ csr,
                                                        const unsigned* __restrict__ rowptr,
                                                        const float* __restrict__ invcnt,
                                                        const float* __restrict__ b,
                                                        const float* __restrict__ U,
                                                        const float* __restrict__ c,
                                                        float* __restrict__ hnext) {
    __shared__ float Ulds[(IN1 + 64) * 64];    // <=32 KiB
    __shared__ float aggL[4][64];
    __shared__ float hpL[4][IN1];
    const int tid = threadIdx.x;
    for (int i = tid; i < (IN1 + 64) * 64; i += 256) Ulds[i] = U[i];
    const int w = tid >> 6, lane = tid & 63;
    const int n = blockIdx.x * 4 + w;

    float acc = y[n * 64 + lane];              // self loop
    unsigned e0 = rowptr[n], e1 = rowptr[n + 1];
    unsigned e = e0;
    for (; e + 4 <= e1; e += 4) {              // 4-way unroll for load ILP
        unsigned s0 = csr[e], s1 = csr[e + 1], s2 = csr[e + 2], s3 = csr[e + 3];
        float a0 = y[s0 * 64 + lane];
        float a1 = y[s1 * 64 + lane];
        float a2 = y[s2 * 64 + lane];
        float a3 = y[s3 * 64 + lane];
        acc += (a0 + a1) + (a2 + a3);
    }
    for (; e < e1; ++e) acc += y[csr[e] * 64 + lane];

    aggL[w][lane] = acc * invcnt[n] + b[lane];
    if (lane < IN1) hpL[w][lane] = hprev[n * IN1 + lane];
    __syncthreads();

    float out = c[lane];
#pragma unroll
    for (int i = 0; i < IN1; ++i) out += hpL[w][i] * Ulds[i * 64 + lane];
#pragma unroll 8
    for (int i = 0; i < 64; ++i) out += aggL[w][i] * Ulds[(IN1 + i) * 64 + lane];
    hnext[n * 64 + lane] = fmaxf(out, 0.f);
}

// ---------------------------------------------------------------- heads

__global__ __launch_bounds__(256) void heads_kernel(const float* __restrict__ h,
                                                    const float* __restrict__ Ws,
                                                    const float* __restrict__ bs,
                                                    const float* __restrict__ Wst,
                                                    const float* __restrict__ bst,
                                                    const float* __restrict__ Wo,
                                                    const float* __restrict__ bo,
                                                    float* __restrict__ state,
                                                    float* __restrict__ part) {
    const int tid = threadIdx.x, w = tid >> 6, lane = tid & 63;
    const int n = blockIdx.x * 4 + w;
    float hv = h[n * 64 + lane];
    float s0 = hv * Ws[lane * 2 + 0];
    float s1 = hv * Ws[lane * 2 + 1];
    float st = hv * Wst[lane];
    float oc = hv * Wo[lane];
#pragma unroll
    for (int off = 32; off; off >>= 1) {
        s0 += __shfl_down(s0, off);
        s1 += __shfl_down(s1, off);
        st += __shfl_down(st, off);
        oc += __shfl_down(oc, off);
    }
    __shared__ float red[4][2];
    if (lane == 0) {
        state[n * 2 + 0] = s0 + bs[0];
        state[n * 2 + 1] = s1 + bs[1];
        red[w][0] = 1.0f / (1.0f + __expf(-(st + bst[0])));
        red[w][1] = oc + bo[0];
    }
    __syncthreads();
    if (tid == 0) {
        part[blockIdx.x * 2 + 0] = red[0][0] + red[1][0] + red[2][0] + red[3][0];
        part[blockIdx.x * 2 + 1] = red[0][1] + red[1][1] + red[2][1] + red[3][1];
    }
}

__global__ __launch_bounds__(1024) void final_reduce(const float* __restrict__ part,
                                                     float* __restrict__ scal) {
    __shared__ float l0[1024], l1[1024];
    const int t = threadIdx.x;
    float a = 0.f, b = 0.f;
    for (int i = t; i < NODE_BLOCKS; i += 1024) { a += part[2 * i]; b += part[2 * i + 1]; }
    l0[t] = a; l1[t] = b;
    __syncthreads();
    for (int off = 512; off; off >>= 1) {
        if (t < off) { l0[t] += l0[t + off]; l1[t] += l1[t + off]; }
        __syncthreads();
    }
    if (t == 0) {
        scal[0] = l0[0] / (float)N_NODES;   // stability
        scal[1] = l1[0] / (float)N_NODES;   // opf_cost
    }
}

// ---------------------------------------------------------------- launch

extern "C" void kernel_launch(void* const* d_in, const int* in_sizes, int n_in,
                              void* d_out, int out_size, void* d_ws, size_t ws_size,
                              hipStream_t stream) {
    const float* x   = (const float*)d_in[0];
    const int*   ei  = (const int*)d_in[1];
    const float* W1  = (const float*)d_in[2];
    const float* b1  = (const float*)d_in[3];
    const float* U1  = (const float*)d_in[4];
    const float* c1  = (const float*)d_in[5];
    const float* W2  = (const float*)d_in[6];
    const float* b2  = (const float*)d_in[7];
    const float* U2  = (const float*)d_in[8];
    const float* c2  = (const float*)d_in[9];
    const float* W3  = (const float*)d_in[10];
    const float* b3  = (const float*)d_in[11];
    const float* U3  = (const float*)d_in[12];
    const float* c3  = (const float*)d_in[13];
    const float* Ws  = (const float*)d_in[14];
    const float* bs  = (const float*)d_in[15];
    const float* Wst = (const float*)d_in[16];
    const float* bst = (const float*)d_in[17];
    const float* Wo  = (const float*)d_in[18];
    const float* bo  = (const float*)d_in[19];

    const int* src = ei;              // edge_index[0]
    const int* dst = ei + N_EDGES;    // edge_index[1]

    // workspace layout (256-byte aligned regions; each zeroed to its own extent)
    char* wsp = (char*)d_ws;
    size_t off = 0;
    auto alloc = [&](size_t bytes) -> char* {
        char* p = wsp + off;
        off = (off + bytes + 255) & ~(size_t)255;
        return p;
    };
    unsigned* cnt    = (unsigned*)alloc((size_t)N_NODES * 4);
    unsigned* fillc  = (unsigned*)alloc((size_t)N_NODES * 4);
    unsigned* rowptr = (unsigned*)alloc((size_t)(N_NODES + 1) * 4);
    float*    invcnt = (float*)   alloc((size_t)N_NODES * 4);
    unsigned* csr    = (unsigned*)alloc((size_t)N_EDGES * 4);
    float*    part   = (float*)   alloc((size_t)NODE_BLOCKS * 2 * 4);
    float*    ybuf   = (float*)   alloc((size_t)N_NODES * HIDDEN * 4);
    float*    hA     = (float*)   alloc((size_t)N_NODES * HIDDEN * 4);
    float*    hB     = (float*)   alloc((size_t)N_NODES * HIDDEN * 4);

    float* out   = (float*)d_out;
    float* state = out;                 // [N, 2]
    float* scal  = out + 200000;        // stability, opf_cost
    float* hout  = out + 200002;        // [N, 64]

    const int EB = (N_EDGES + 255) / 256;   // 4688
    const int NB = (N_NODES + 255) / 256;   // 391

    // CSR build (reused by all 3 layers).
    // NOTE: zero cnt and fillc with exact extents — regions are 256B-aligned,
    // NOT contiguous (one combined zero left poison in fillc's tail last round).
    zero_u32<<<NB, 256, 0, stream>>>(cnt,   N_NODES);
    zero_u32<<<NB, 256, 0, stream>>>(fillc, N_NODES);
    hist_kernel<<<EB, 256, 0, stream>>>(dst, cnt);
    scan_kernel<<<1, 1024, 0, stream>>>(cnt, rowptr, invcnt);
    fill_csr<<<EB, 256, 0, stream>>>(src, dst, rowptr, fillc, csr);

    // layer 1 (in = 5)
    linear_y<5><<<NODE_BLOCKS, 256, 0, stream>>>(x, W1, ybuf);
    fused_agg_update<5><<<NODE_BLOCKS, 256, 0, stream>>>(x, ybuf, csr, rowptr, invcnt,
                                                         b1, U1, c1, hA);
    // layer 2 (in = 64)
    linear_y<64><<<NODE_BLOCKS, 256, 0, stream>>>(hA, W2, ybuf);
    fused_agg_update<64><<<NODE_BLOCKS, 256, 0, stream>>>(hA, ybuf, csr, rowptr, invcnt,
                                                          b2, U2, c2, hB);
    // layer 3 (in = 64) — h written straight into d_out
    linear_y<64><<<NODE_BLOCKS, 256, 0, stream>>>(hB, W3, ybuf);
    fused_agg_update<64><<<NODE_BLOCKS, 256, 0, stream>>>(hB, ybuf, csr, rowptr, invcnt,
                                                          b3, U3, c3, hout);
    // heads
    heads_kernel<<<NODE_BLOCKS, 256, 0, stream>>>(hout, Ws, bs, Wst, bst, Wo, bo, state, part);
    final_reduce<<<1, 1024, 0, stream>>>(part, scal);
}

// Round 3
// 823.117 us; speedup vs baseline: 1.2598x; 1.2598x over previous
//
#include <hip/hip_runtime.h>
#include <math.h>

#define N_NODES 100000
#define N_EDGES 1200000
#define HIDDEN  64
#define NODE_BLOCKS (N_NODES / 4)   // 25000, exact: 4 nodes (waves) per 256-thread block
#define SCAN_BLOCKS ((N_NODES + 1023) / 1024)   // 98

// ---------------------------------------------------------------- utilities

__global__ __launch_bounds__(256) void zero_u32(unsigned* __restrict__ p, int n) {
    int i = blockIdx.x * 256 + threadIdx.x;
    if (i < n) p[i] = 0u;
}

// ---------------------------------------------------------------- CSR build

__global__ __launch_bounds__(256) void hist_kernel(const int* __restrict__ dst,
                                                   unsigned* __restrict__ cnt) {
    int e = blockIdx.x * 256 + threadIdx.x;
    if (e < N_EDGES) atomicAdd(&cnt[dst[e]], 1u);
}

// Multi-block scan, phase 1: per-block (1024 elems) exclusive prefix + block sum.
// N_NODES % 4 == 0, so each thread's 4-element group is fully in- or out-of-range.
__global__ __launch_bounds__(256) void scan_partial(const unsigned* __restrict__ cnt,
                                                    unsigned* __restrict__ pre,
                                                    unsigned* __restrict__ bsum) {
    __shared__ unsigned lds[256];
    const int t = threadIdx.x;
    const int base = blockIdx.x * 1024 + t * 4;
    unsigned v0 = 0, v1 = 0, v2 = 0, v3 = 0;
    if (base < N_NODES) {
        const uint4 q = *(const uint4*)(cnt + base);
        v0 = q.x; v1 = q.y; v2 = q.z; v3 = q.w;
    }
    const unsigned s = v0 + v1 + v2 + v3;
    lds[t] = s;
    __syncthreads();
    for (int off = 1; off < 256; off <<= 1) {   // Hillis-Steele over 256
        unsigned u = (t >= off) ? lds[t - off] : 0u;
        __syncthreads();
        lds[t] += u;
        __syncthreads();
    }
    const unsigned excl = lds[t] - s;
    if (base < N_NODES) {
        uint4 o;
        o.x = excl;
        o.y = excl + v0;
        o.z = excl + v0 + v1;
        o.w = excl + v0 + v1 + v2;
        *(uint4*)(pre + base) = o;
    }
    if (t == 255) bsum[blockIdx.x] = lds[255];
}

// phase 2: exclusive scan of the 98 block sums, in place (single tiny block).
__global__ __launch_bounds__(128) void scan_bsum(unsigned* __restrict__ bsum) {
    __shared__ unsigned lds[128];
    const int t = threadIdx.x;
    unsigned s = (t < SCAN_BLOCKS) ? bsum[t] : 0u;
    lds[t] = s;
    __syncthreads();
    for (int off = 1; off < 128; off <<= 1) {
        unsigned u = (t >= off) ? lds[t - off] : 0u;
        __syncthreads();
        lds[t] += u;
        __syncthreads();
    }
    if (t < SCAN_BLOCKS) bsum[t] = lds[t] - s;
}

// phase 3: rowptr = pre + block offset; invcnt = 1/(cnt+1). All coalesced uint4.
__global__ __launch_bounds__(256) void scan_final(const unsigned* __restrict__ cnt,
                                                  const unsigned* __restrict__ pre,
                                                  const unsigned* __restrict__ bsum,
                                                  unsigned* __restrict__ rowptr,
                                                  float* __restrict__ invcnt) {
    const int t = threadIdx.x;
    const int base = blockIdx.x * 1024 + t * 4;
    if (base < N_NODES) {
        const unsigned off = bsum[blockIdx.x];
        uint4 p = *(const uint4*)(pre + base);
        const uint4 cq = *(const uint4*)(cnt + base);
        p.x += off; p.y += off; p.z += off; p.w += off;
        *(uint4*)(rowptr + base) = p;
        float4 ic;
        ic.x = 1.0f / (float)(cq.x + 1u);
        ic.y = 1.0f / (float)(cq.y + 1u);
        ic.z = 1.0f / (float)(cq.z + 1u);
        ic.w = 1.0f / (float)(cq.w + 1u);
        *(float4*)(invcnt + base) = ic;
    }
    if (blockIdx.x == 0 && t == 0) rowptr[N_NODES] = N_EDGES;
}

__global__ __launch_bounds__(256) void fill_csr(const int* __restrict__ src,
                                                const int* __restrict__ dst,
                                                const unsigned* __restrict__ rowptr,
                                                unsigned* __restrict__ fillc,
                                                unsigned* __restrict__ csr) {
    int e = blockIdx.x * 256 + threadIdx.x;
    if (e < N_EDGES) {
        int d = dst[e];
        unsigned pos = rowptr[d] + atomicAdd(&fillc[d], 1u);
        csr[pos] = (unsigned)src[e];
    }
}

// ---------------------------------------------------------------- per-layer

// y[n,:] = hprev[n,:] @ W   (W: [IN1, 64] row-major, no bias — bias folded post-mean)
template <int IN1>
__global__ __launch_bounds__(256) void linear_y(const float* __restrict__ hprev,
                                                const float* __restrict__ W,
                                                float* __restrict__ y) {
    __shared__ float Wl[IN1 * 64];
    __shared__ float hpL[4][IN1];
    const int tid = threadIdx.x;
    for (int i = tid; i < IN1 * 64; i += 256) Wl[i] = W[i];
    const int w = tid >> 6, lane = tid & 63;
    const int n = blockIdx.x * 4 + w;          // N divisible by 4; grid exact
    if (lane < IN1) hpL[w][lane] = hprev[n * IN1 + lane];
    __syncthreads();
    float acc = 0.f;
#pragma unroll
    for (int i = 0; i < IN1; ++i) acc += hpL[w][i] * Wl[i * 64 + lane];
    y[n * 64 + lane] = acc;
}

// agg[n,:] = (y[n,:] + sum_{e in-edges} y[src_e,:]) * invcnt[n] + b
// hnext[n,:] = relu( [hprev[n,:], agg[n,:]] @ U + c )     (U: [IN1+64, 64] row-major)
template <int IN1>
__global__ __launch_bounds__(256) void fused_agg_update(const float* __restrict__ hprev,
                                                        const float* __restrict__ y,
                                                        const unsigned* __restrict__ csr,
                                                        const unsigned* __restrict__ rowptr,
                                                        const float* __restrict__ invcnt,
                                                        const float* __restrict__ b,
                                                        const float* __restrict__ U,
                                                        const float* __restrict__ c,
                                                        float* __restrict__ hnext) {
    __shared__ float Ulds[(IN1 + 64) * 64];    // <=32 KiB
    __shared__ float aggL[4][64];
    __shared__ float hpL[4][IN1];
    const int tid = threadIdx.x;
    for (int i = tid; i < (IN1 + 64) * 64; i += 256) Ulds[i] = U[i];
    const int w = tid >> 6, lane = tid & 63;
    const int n = blockIdx.x * 4 + w;

    float acc = y[n * 64 + lane];              // self loop
    unsigned e0 = rowptr[n], e1 = rowptr[n + 1];
    unsigned e = e0;
    for (; e + 4 <= e1; e += 4) {              // 4-way unroll for load ILP
        unsigned s0 = csr[e], s1 = csr[e + 1], s2 = csr[e + 2], s3 = csr[e + 3];
        float a0 = y[s0 * 64 + lane];
        float a1 = y[s1 * 64 + lane];
        float a2 = y[s2 * 64 + lane];
        float a3 = y[s3 * 64 + lane];
        acc += (a0 + a1) + (a2 + a3);
    }
    for (; e < e1; ++e) acc += y[csr[e] * 64 + lane];

    aggL[w][lane] = acc * invcnt[n] + b[lane];
    if (lane < IN1) hpL[w][lane] = hprev[n * IN1 + lane];
    __syncthreads();

    float out = c[lane];
#pragma unroll
    for (int i = 0; i < IN1; ++i) out += hpL[w][i] * Ulds[i * 64 + lane];
#pragma unroll 8
    for (int i = 0; i < 64; ++i) out += aggL[w][i] * Ulds[(IN1 + i) * 64 + lane];
    hnext[n * 64 + lane] = fmaxf(out, 0.f);
}

// ---------------------------------------------------------------- heads

__global__ __launch_bounds__(256) void heads_kernel(const float* __restrict__ h,
                                                    const float* __restrict__ Ws,
                                                    const float* __restrict__ bs,
                                                    const float* __restrict__ Wst,
                                                    const float* __restrict__ bst,
                                                    const float* __restrict__ Wo,
                                                    const float* __restrict__ bo,
                                                    float* __restrict__ state,
                                                    float* __restrict__ part) {
    const int tid = threadIdx.x, w = tid >> 6, lane = tid & 63;
    const int n = blockIdx.x * 4 + w;
    float hv = h[n * 64 + lane];
    float s0 = hv * Ws[lane * 2 + 0];
    float s1 = hv * Ws[lane * 2 + 1];
    float st = hv * Wst[lane];
    float oc = hv * Wo[lane];
#pragma unroll
    for (int off = 32; off; off >>= 1) {
        s0 += __shfl_down(s0, off);
        s1 += __shfl_down(s1, off);
        st += __shfl_down(st, off);
        oc += __shfl_down(oc, off);
    }
    __shared__ float red[4][2];
    if (lane == 0) {
        state[n * 2 + 0] = s0 + bs[0];
        state[n * 2 + 1] = s1 + bs[1];
        red[w][0] = 1.0f / (1.0f + __expf(-(st + bst[0])));
        red[w][1] = oc + bo[0];
    }
    __syncthreads();
    if (tid == 0) {
        part[blockIdx.x * 2 + 0] = red[0][0] + red[1][0] + red[2][0] + red[3][0];
        part[blockIdx.x * 2 + 1] = red[0][1] + red[1][1] + red[2][1] + red[3][1];
    }
}

__global__ __launch_bounds__(1024) void final_reduce(const float* __restrict__ part,
                                                     float* __restrict__ scal) {
    __shared__ float l0[1024], l1[1024];
    const int t = threadIdx.x;
    float a = 0.f, b = 0.f;
    for (int i = t; i < NODE_BLOCKS; i += 1024) { a += part[2 * i]; b += part[2 * i + 1]; }
    l0[t] = a; l1[t] = b;
    __syncthreads();
    for (int off = 512; off; off >>= 1) {
        if (t < off) { l0[t] += l0[t + off]; l1[t] += l1[t + off]; }
        __syncthreads();
    }
    if (t == 0) {
        scal[0] = l0[0] / (float)N_NODES;   // stability
        scal[1] = l1[0] / (float)N_NODES;   // opf_cost
    }
}

// ---------------------------------------------------------------- launch

extern "C" void kernel_launch(void* const* d_in, const int* in_sizes, int n_in,
                              void* d_out, int out_size, void* d_ws, size_t ws_size,
                              hipStream_t stream) {
    const float* x   = (const float*)d_in[0];
    const int*   ei  = (const int*)d_in[1];
    const float* W1  = (const float*)d_in[2];
    const float* b1  = (const float*)d_in[3];
    const float* U1  = (const float*)d_in[4];
    const float* c1  = (const float*)d_in[5];
    const float* W2  = (const float*)d_in[6];
    const float* b2  = (const float*)d_in[7];
    const float* U2  = (const float*)d_in[8];
    const float* c2  = (const float*)d_in[9];
    const float* W3  = (const float*)d_in[10];
    const float* b3  = (const float*)d_in[11];
    const float* U3  = (const float*)d_in[12];
    const float* c3  = (const float*)d_in[13];
    const float* Ws  = (const float*)d_in[14];
    const float* bs  = (const float*)d_in[15];
    const float* Wst = (const float*)d_in[16];
    const float* bst = (const float*)d_in[17];
    const float* Wo  = (const float*)d_in[18];
    const float* bo  = (const float*)d_in[19];

    const int* src = ei;              // edge_index[0]
    const int* dst = ei + N_EDGES;    // edge_index[1]

    // workspace layout (256-byte aligned regions; each zeroed to its own extent)
    char* wsp = (char*)d_ws;
    size_t off = 0;
    auto alloc = [&](size_t bytes) -> char* {
        char* p = wsp + off;
        off = (off + bytes + 255) & ~(size_t)255;
        return p;
    };
    unsigned* cnt    = (unsigned*)alloc((size_t)N_NODES * 4);
    unsigned* fillc  = (unsigned*)alloc((size_t)N_NODES * 4);
    unsigned* rowptr = (unsigned*)alloc((size_t)(N_NODES + 1) * 4);
    float*    invcnt = (float*)   alloc((size_t)N_NODES * 4);
    unsigned* pre    = (unsigned*)alloc((size_t)N_NODES * 4);
    unsigned* bsum   = (unsigned*)alloc((size_t)SCAN_BLOCKS * 4);
    unsigned* csr    = (unsigned*)alloc((size_t)N_EDGES * 4);
    float*    part   = (float*)   alloc((size_t)NODE_BLOCKS * 2 * 4);
    float*    ybuf   = (float*)   alloc((size_t)N_NODES * HIDDEN * 4);
    float*    hA     = (float*)   alloc((size_t)N_NODES * HIDDEN * 4);
    float*    hB     = (float*)   alloc((size_t)N_NODES * HIDDEN * 4);

    float* out   = (float*)d_out;
    float* state = out;                 // [N, 2]
    float* scal  = out + 200000;        // stability, opf_cost
    float* hout  = out + 200002;        // [N, 64]

    const int EB = (N_EDGES + 255) / 256;   // 4688
    const int NB = (N_NODES + 255) / 256;   // 391

    // CSR build (reused by all 3 layers).
    // NOTE: zero cnt and fillc with exact extents — regions are 256B-aligned,
    // NOT contiguous (one combined zero left poison in fillc's tail in R1).
    zero_u32<<<NB, 256, 0, stream>>>(cnt,   N_NODES);
    zero_u32<<<NB, 256, 0, stream>>>(fillc, N_NODES);
    hist_kernel<<<EB, 256, 0, stream>>>(dst, cnt);
    scan_partial<<<SCAN_BLOCKS, 256, 0, stream>>>(cnt, pre, bsum);
    scan_bsum<<<1, 128, 0, stream>>>(bsum);
    scan_final<<<SCAN_BLOCKS, 256, 0, stream>>>(cnt, pre, bsum, rowptr, invcnt);
    fill_csr<<<EB, 256, 0, stream>>>(src, dst, rowptr, fillc, csr);

    // layer 1 (in = 5)
    linear_y<5><<<NODE_BLOCKS, 256, 0, stream>>>(x, W1, ybuf);
    fused_agg_update<5><<<NODE_BLOCKS, 256, 0, stream>>>(x, ybuf, csr, rowptr, invcnt,
                                                         b1, U1, c1, hA);
    // layer 2 (in = 64)
    linear_y<64><<<NODE_BLOCKS, 256, 0, stream>>>(hA, W2, ybuf);
    fused_agg_update<64><<<NODE_BLOCKS, 256, 0, stream>>>(hA, ybuf, csr, rowptr, invcnt,
                                                          b2, U2, c2, hB);
    // layer 3 (in = 64) — h written straight into d_out
    linear_y<64><<<NODE_BLOCKS, 256, 0, stream>>>(hB, W3, ybuf);
    fused_agg_update<64><<<NODE_BLOCKS, 256, 0, stream>>>(hB, ybuf, csr, rowptr, invcnt,
                                                          b3, U3, c3, hout);
    // heads
    heads_kernel<<<NODE_BLOCKS, 256, 0, stream>>>(hout, Ws, bs, Wst, bst, Wo, bo, state, part);
    final_reduce<<<1, 1024, 0, stream>>>(part, scal);
}